// Round 3
// baseline (3149.288 us; speedup 1.0000x reference)
//
#include <hip/hip_runtime.h>
#include <math.h>

#define PP 262144   // 512*512
#define WW 512
#define EPSLN 1e-5f
#define RSTRIPE 128
#define STR 70656   // (RSTRIPE+10)*512

// ---------------- workspace layout (float offsets), total 52,205,568 floats = 208.8 MB ----
#define OFF_Y     0
#define OFF_XO    0
#define OFF_HIGH  16777216
#define OFF_T4    33554432
#define OFF_PINS  16777216
#define OFF_XD    50331648
#define OFF_QKV0  50593792
#define OFF_QKVB  51380224
#define OFF_RNORM 52166656
#define OFF_ATTN  52166784
#define OFF_VMAX  52168832
#define OFF_VMEAN 52168896
#define OFF_V2    52168960
#define OFF_M2T   52169024
#define OFF_C1T   52173120
#define OFF_PJT   52181312
#define OFF_C4T   52185408
#define OFF_FOT   52189504
#define OFF_K1    52200384
#define OFF_K2    52202944
#define OFF_HC    52205504
#define WS_NEEDED_FLOATS 52205568

// ---------------- weight transposes (tiny, once per launch) ----------------
__global__ __launch_bounds__(256) void k_wT(const float* __restrict__ c1, const float* __restrict__ pj,
                     const float* __restrict__ c4, const float* __restrict__ fo,
                     float* __restrict__ c1T, float* __restrict__ pjT,
                     float* __restrict__ c4T, float* __restrict__ foT) {
  int t = blockIdx.x * 256 + threadIdx.x;
  if (t < 8192)  c1T[(t & 127) * 64 + (t >> 7)] = c1[t];       // (64,128) -> [c][o]
  if (t < 8192 && (t & 127) < 64) pjT[(t & 127) * 64 + (t >> 7)] = pj[t];  // high half only
  if (t < 4096)  c4T[(t & 63) * 64 + (t >> 6)]  = c4[t];       // (64,64)  -> [c][o]
  if (t < 10880) foT[(t % 170) * 64 + (t / 170)] = fo[t];      // (64,170) -> [hc][o]
}

// ---------------- composite 3x13 / 13x3 kernels + constant term ----------------
// K1_c = dw3(g_c over ch c) conv dw1x11(k_c) ; K2_c = dw3(g_{64+c}) conv dw11x1
// hconst[o] = sum_c c1[o][c]*(b3[c]+wwb[c]*sum(g_c)) + c1[o][64+c]*(b3[64+c]+whb[c]*sum(g_{64+c}))
__global__ __launch_bounds__(256) void k_prep(const float* __restrict__ ww, const float* __restrict__ wwb,
    const float* __restrict__ wh, const float* __restrict__ whb,
    const float* __restrict__ w3, const float* __restrict__ b3,
    const float* __restrict__ c1,
    float* __restrict__ K1, float* __restrict__ K2, float* __restrict__ HC) {
  int t = blockIdx.x * 256 + threadIdx.x;
  if (t < 2496) {                       // K1: 64 ch x (3 rows x 13 cols)
    int c = t / 39, r = t % 39, ey = r / 13, ex = r % 13;
    float s = 0.f;
    for (int dx = 0; dx < 3; ++dx) {
      int j = ex - dx;                  // = (ex-6) - (dx-1) + 5
      if (j >= 0 && j < 11) s += w3[c * 9 + ey * 3 + dx] * ww[c * 11 + j];
    }
    K1[c * 40 + r] = s;
  } else if (t < 4992) {                // K2: 64 ch x (13 rows x 3 cols)
    int u = t - 2496;
    int c = u / 39, r = u % 39, ey = r / 3, ex = r % 3;
    float s = 0.f;
    for (int dy = 0; dy < 3; ++dy) {
      int j = ey - dy;
      if (j >= 0 && j < 11) s += w3[(64 + c) * 9 + dy * 3 + ex] * wh[c * 11 + j];
    }
    K2[c * 40 + r] = s;
  } else if (t < 5056) {                // hconst[o]
    int o = t - 4992;
    float s = 0.f;
    for (int c = 0; c < 64; ++c) {
      float g1 = 0.f, g2 = 0.f;
      for (int k = 0; k < 9; ++k) { g1 += w3[c * 9 + k]; g2 += w3[(64 + c) * 9 + k]; }
      float cA = b3[c] + wwb[c] * g1;
      float cB = b3[64 + c] + whb[c] * g2;
      s += c1[o * 128 + c] * cA + c1[o * 128 + 64 + c] * cB;
    }
    HC[o] = s;
  }
}

// ---------------- LayerNorm over channels (thread = pixel) ----------------
__global__ __launch_bounds__(256) void k_ln1(const float* __restrict__ x,
    const float* __restrict__ w, const float* __restrict__ b, float* __restrict__ y) {
  int p = blockIdx.x * 256 + threadIdx.x;
  float v[64]; float mu = 0.f;
  #pragma unroll
  for (int c = 0; c < 64; ++c) { v[c] = x[c * PP + p]; mu += v[c]; }
  mu *= (1.f / 64.f);
  float s = 0.f;
  #pragma unroll
  for (int c = 0; c < 64; ++c) { float d = v[c] - mu; s += d * d; }
  float rs = rsqrtf(s * (1.f / 64.f) + EPSLN);
  #pragma unroll
  for (int c = 0; c < 64; ++c) y[c * PP + p] = (v[c] - mu) * rs * w[c] + b[c];
}

// ---------------- 8x8 avg pool of y -> xd (64x64x64) ----------------
__global__ __launch_bounds__(256) void k_pool(const float* __restrict__ y, float* __restrict__ xd) {
  int t = blockIdx.x * 256 + threadIdx.x;
  int c = t >> 12, cell = t & 4095;
  int cy = cell >> 6, cx = cell & 63;
  const float* base = y + c * PP + (cy * 8) * WW + cx * 8;
  float s = 0.f;
  #pragma unroll
  for (int r = 0; r < 8; ++r)
    #pragma unroll
    for (int i = 0; i < 8; ++i) s += base[r * WW + i];
  xd[t] = s * (1.f / 64.f);
}

// ---------------- qkv 1x1 conv 64->192 on 64x64 ----------------
__global__ __launch_bounds__(256) void k_qkv0(const float* __restrict__ xd,
    const float* __restrict__ w, float* __restrict__ q0) {
  int t = blockIdx.x * 256 + threadIdx.x;
  int o = t >> 12, pd = t & 4095;
  float acc = 0.f;
  #pragma unroll
  for (int c = 0; c < 64; ++c) acc += w[o * 64 + c] * xd[c * 4096 + pd];
  q0[t] = acc;
}

// ---------------- qkv depthwise 3x3 (192 ch, 64x64, pad1, no bias) ----------------
__global__ __launch_bounds__(256) void k_qkvdw(const float* __restrict__ q0,
    const float* __restrict__ w, float* __restrict__ qb) {
  int t = blockIdx.x * 256 + threadIdx.x;
  int o = t >> 12, pd = t & 4095;
  int yy = pd >> 6, xx = pd & 63;
  float acc = 0.f;
  #pragma unroll
  for (int dy = 0; dy < 3; ++dy) {
    int iy = yy + dy - 1;
    if (iy < 0 || iy >= 64) continue;
    #pragma unroll
    for (int dx = 0; dx < 3; ++dx) {
      int ix = xx + dx - 1;
      if (ix < 0 || ix >= 64) continue;
      acc += w[o * 9 + dy * 3 + dx] * q0[o * 4096 + iy * 64 + ix];
    }
  }
  qb[t] = acc;
}

// ---------------- 1/L2norm of q,k rows (128 rows x 4096) ----------------
__global__ __launch_bounds__(256) void k_qknorm(const float* __restrict__ qb, float* __restrict__ rnorm) {
  int r = blockIdx.x;
  const float* row = qb + r * 4096;
  float s = 0.f;
  for (int i = threadIdx.x; i < 4096; i += 256) { float v = row[i]; s += v * v; }
  __shared__ float red[256];
  red[threadIdx.x] = s; __syncthreads();
  for (int off = 128; off > 0; off >>= 1) {
    if (threadIdx.x < off) red[threadIdx.x] += red[threadIdx.x + off];
    __syncthreads();
  }
  if (threadIdx.x == 0) rnorm[r] = 1.f / fmaxf(sqrtf(red[0]), 1e-12f);
}

// ---------------- attn row (h,c): 32 dots over 4096 + softmax ----------------
__global__ __launch_bounds__(256) void k_attn(const float* __restrict__ qb,
    const float* __restrict__ rnorm, const float* __restrict__ temp, float* __restrict__ attn) {
  int h = blockIdx.x >> 5, c = blockIdx.x & 31;
  const float* qrow = qb + (h * 32 + c) * 4096;
  const float* kb   = qb + (64 + h * 32) * 4096;
  float acc[32];
  #pragma unroll
  for (int d = 0; d < 32; ++d) acc[d] = 0.f;
  for (int pd = threadIdx.x; pd < 4096; pd += 256) {
    float qv = qrow[pd];
    #pragma unroll
    for (int d = 0; d < 32; ++d) acc[d] += qv * kb[d * 4096 + pd];
  }
  __shared__ float red[32][257];
  __shared__ float srow[32];
  #pragma unroll
  for (int d = 0; d < 32; ++d) red[d][threadIdx.x] = acc[d];
  __syncthreads();
  if (threadIdx.x < 32) {
    int d = threadIdx.x;
    float s = 0.f;
    for (int j = 0; j < 256; ++j) s += red[d][j];
    s *= rnorm[h * 32 + c] * rnorm[64 + h * 32 + d] * temp[h];
    srow[d] = s;
  }
  __syncthreads();
  if (threadIdx.x == 0) {
    float m = srow[0];
    for (int d = 1; d < 32; ++d) m = fmaxf(m, srow[d]);
    float sum = 0.f;
    float e[32];
    for (int d = 0; d < 32; ++d) { e[d] = expf(srow[d] - m); sum += e[d]; }
    float r = 1.f / sum;
    for (int d = 0; d < 32; ++d) attn[(h * 32 + c) * 32 + d] = e[d] * r;
  }
}

// ---------------- v spatial max/mean per channel ----------------
__global__ __launch_bounds__(256) void k_vstat(const float* __restrict__ qb,
    float* __restrict__ vmax, float* __restrict__ vmean) {
  int ci = blockIdx.x;
  const float* row = qb + (128 + ci) * 4096;
  float mx = -1e30f, s = 0.f;
  for (int i = threadIdx.x; i < 4096; i += 256) { float v = row[i]; mx = fmaxf(mx, v); s += v; }
  __shared__ float rm[256], rs[256];
  rm[threadIdx.x] = mx; rs[threadIdx.x] = s; __syncthreads();
  for (int off = 128; off > 0; off >>= 1) {
    if (threadIdx.x < off) {
      rm[threadIdx.x] = fmaxf(rm[threadIdx.x], rm[threadIdx.x + off]);
      rs[threadIdx.x] += rs[threadIdx.x + off];
    }
    __syncthreads();
  }
  if (threadIdx.x == 0) { vmax[ci] = rm[0]; vmean[ci] = rs[0] * (1.f / 4096.f); }
}

// ---------------- v2[c] = conv2(vmax) + conv3(vmean) ----------------
__global__ void k_v2(const float* __restrict__ vmax, const float* __restrict__ vmean,
    const float* __restrict__ w2, const float* __restrict__ w3, float* __restrict__ v2) {
  int c = threadIdx.x;
  float s = 0.f;
  #pragma unroll
  for (int ci = 0; ci < 64; ++ci) s += w2[c * 64 + ci] * vmax[ci] + w3[c * 64 + ci] * vmean[ci];
  v2[c] = s;
}

// ---------------- M2[o,c=h*32+d], stored [c][o] ----------------
__global__ __launch_bounds__(256) void k_m2(const float* __restrict__ attn,
    const float* __restrict__ pj, float* __restrict__ m2T) {
  int t = blockIdx.x * 256 + threadIdx.x;   // 4096
  int o = t >> 6, c = t & 63;
  int h = c >> 5, d = c & 31;
  float s = 0.f;
  #pragma unroll
  for (int cc = 0; cc < 32; ++cc)
    s += pj[o * 128 + 64 + h * 32 + cc] * attn[(h * 32 + cc) * 32 + d];
  m2T[c * 64 + o] = s;
}

// ---------------- fused high path: interior = composite 3x13/13x3 + 1x1; boundary = exact ring ----
__global__ __launch_bounds__(256) void k_dwhigh(const float* __restrict__ y,
    const float* __restrict__ ww, const float* __restrict__ wwb,
    const float* __restrict__ wh, const float* __restrict__ whb,
    const float* __restrict__ w3, const float* __restrict__ b3,
    const float* __restrict__ c1T,
    const float* __restrict__ K1, const float* __restrict__ K2,
    const float* __restrict__ HC, float* __restrict__ high) {
  int bx = blockIdx.x & 31, by = blockIdx.x >> 5;
  int x0 = bx * 16, y0 = by * 16;
  int tx = threadIdx.x & 15, ty = threadIdx.x >> 4;
  int t = threadIdx.x;
  __shared__ float tyy[2][28][40];    // stride 40: 2 lanes/bank on reads (free)
  __shared__ float ha[18][18];
  __shared__ float hb[18][18];
  float acc[64];
  bool interior = (bx > 0 && bx < 31 && by > 0 && by < 31);
  int p = (y0 + ty) * 512 + x0 + tx;

  if (interior) {
    #pragma unroll
    for (int o = 0; o < 64; ++o) acc[o] = HC[o];
    // staging geometry: 28 rows x 8 float4 (32 cols), origin (y0-6, x0-8), 16B-aligned
    int srow = t >> 3, sq = t & 7;
    const float* gsrc = y + (y0 - 6 + srow) * 512 + (x0 - 8) + sq * 4;
    if (t < 224) *(float4*)&tyy[0][srow][sq * 4] = *(const float4*)gsrc;
    for (int c = 0; c < 64; ++c) {
      int cur = c & 1;
      __syncthreads();
      if (c < 63 && t < 224)
        *(float4*)&tyy[cur ^ 1][srow][sq * 4] = *(const float4*)(gsrc + (c + 1) * PP);
      float SA = 0.f, SB = 0.f;
      const float* k1c = K1 + c * 40;
      const float* k2c = K2 + c * 40;
      #pragma unroll
      for (int ey = 0; ey < 3; ++ey)
        #pragma unroll
        for (int ex = 0; ex < 13; ++ex)
          SA += k1c[ey * 13 + ex] * tyy[cur][ty + 5 + ey][tx + 2 + ex];
      #pragma unroll
      for (int ey = 0; ey < 13; ++ey)
        #pragma unroll
        for (int ex = 0; ex < 3; ++ex)
          SB += k2c[ey * 3 + ex] * tyy[cur][ty + ey][tx + 7 + ex];
      const float* wc1 = c1T + c * 64;
      const float* wc2 = c1T + (64 + c) * 64;
      #pragma unroll
      for (int o = 0; o < 64; ++o) acc[o] += wc1[o] * SA + wc2[o] * SB;
    }
  } else {
    #pragma unroll
    for (int o = 0; o < 64; ++o) acc[o] = 0.f;
    // masked scalar staging: 28 rows x 32 cols, origin (y0-6, x0-8)
    for (int idx = t; idx < 896; idx += 256) {
      int ly = idx >> 5, lx = idx & 31;
      int gy = y0 - 6 + ly, gx = x0 - 8 + lx;
      float v = 0.f;
      if (gy >= 0 && gy < 512 && gx >= 0 && gx < 512) v = y[gy * 512 + gx];
      tyy[0][ly][lx] = v;
    }
    for (int c = 0; c < 64; ++c) {
      int cur = c & 1;
      __syncthreads();
      if (c < 63) {
        for (int idx = t; idx < 896; idx += 256) {
          int ly = idx >> 5, lx = idx & 31;
          int gy = y0 - 6 + ly, gx = x0 - 8 + lx;
          float v = 0.f;
          if (gy >= 0 && gy < 512 && gx >= 0 && gx < 512) v = y[(c + 1) * PP + gy * 512 + gx];
          tyy[cur ^ 1][ly][lx] = v;
        }
      }
      // ring: 18x18 intermediate values at origin (y0-1, x0-1); zero outside image (no bias!)
      for (int idx = t; idx < 324; idx += 256) {
        int ly = idx / 18, lx = idx % 18;
        int gy = y0 - 1 + ly, gx = x0 - 1 + lx;
        float a = 0.f, b = 0.f;
        if (gy >= 0 && gy < 512 && gx >= 0 && gx < 512) {
          a = wwb[c]; b = whb[c];
          #pragma unroll
          for (int i = 0; i < 11; ++i) a += ww[c * 11 + i] * tyy[cur][ly + 5][lx + 2 + i];
          #pragma unroll
          for (int i = 0; i < 11; ++i) b += wh[c * 11 + i] * tyy[cur][ly + i][lx + 7];
        }
        ha[ly][lx] = a; hb[ly][lx] = b;
      }
      __syncthreads();
      float sa = b3[c], sb = b3[64 + c];
      #pragma unroll
      for (int dy = 0; dy < 3; ++dy)
        #pragma unroll
        for (int dx = 0; dx < 3; ++dx) {
          sa += w3[c * 9 + dy * 3 + dx]        * ha[ty + dy][tx + dx];
          sb += w3[(64 + c) * 9 + dy * 3 + dx] * hb[ty + dy][tx + dx];
        }
      const float* wc1 = c1T + c * 64;
      const float* wc2 = c1T + (64 + c) * 64;
      #pragma unroll
      for (int o = 0; o < 64; ++o) acc[o] += wc1[o] * sa + wc2[o] * sb;
    }
  }
  #pragma unroll
  for (int o = 0; o < 64; ++o) high[o * PP + p] = acc[o];
}

// ---------------- conv4a: 1x1 64->64 on y ----------------
__global__ __launch_bounds__(256) void k_conv4a(const float* __restrict__ y,
    const float* __restrict__ c4T, float* __restrict__ t4) {
  int p = blockIdx.x * 256 + threadIdx.x;
  float acc[64];
  #pragma unroll
  for (int o = 0; o < 64; ++o) acc[o] = 0.f;
  for (int c = 0; c < 64; ++c) {
    float vy = y[c * PP + p];
    const float* wc = c4T + c * 64;
    #pragma unroll
    for (int o = 0; o < 64; ++o) acc[o] += wc[o] * vy;
  }
  #pragma unroll
  for (int o = 0; o < 64; ++o) t4[o * PP + p] = acc[o];
}

// ---------------- fused: g=dw3x3(t4); m=v2*g; xo = x + M2@m + projo_high@high ----------------
__global__ __launch_bounds__(256) void k_lowproj(const float* __restrict__ t4,
    const float* __restrict__ w4b, const float* __restrict__ v2,
    const float* __restrict__ m2T, const float* __restrict__ high,
    const float* __restrict__ pjT, const float* __restrict__ x,
    float* __restrict__ xo) {
  int bx = blockIdx.x & 31, by = blockIdx.x >> 5;
  int x0 = bx * 16, y0 = by * 16;
  int tx = threadIdx.x & 15, ty = threadIdx.x >> 4;
  int t = threadIdx.x;
  int p = (y0 + ty) * 512 + x0 + tx;
  __shared__ float tile[2][18][40];   // origin (y0-1, x0-4); stride 40
  bool interior = (bx > 0 && bx < 31 && by > 0 && by < 31);
  float acc[64];
  #pragma unroll
  for (int o = 0; o < 64; ++o) acc[o] = x[o * PP + p];

  int srow = t >> 3, sq = t & 7;      // 18 rows x 8 float4 (32 cols)
  const float* gsrc = t4 + (y0 - 1 + srow) * 512 + (x0 - 4) + sq * 4;
  if (interior) {
    if (t < 144) *(float4*)&tile[0][srow][sq * 4] = *(const float4*)gsrc;
  } else {
    for (int idx = t; idx < 576; idx += 256) {
      int ly = idx >> 5, lx = idx & 31;
      int gy = y0 - 1 + ly, gx = x0 - 4 + lx;
      float v = 0.f;
      if (gy >= 0 && gy < 512 && gx >= 0 && gx < 512) v = t4[gy * 512 + gx];
      tile[0][ly][lx] = v;
    }
  }
  for (int c = 0; c < 64; ++c) {
    int cur = c & 1;
    __syncthreads();
    if (c < 63) {
      if (interior) {
        if (t < 144) *(float4*)&tile[cur ^ 1][srow][sq * 4] = *(const float4*)(gsrc + (c + 1) * PP);
      } else {
        for (int idx = t; idx < 576; idx += 256) {
          int ly = idx >> 5, lx = idx & 31;
          int gy = y0 - 1 + ly, gx = x0 - 4 + lx;
          float v = 0.f;
          if (gy >= 0 && gy < 512 && gx >= 0 && gx < 512) v = t4[(c + 1) * PP + gy * 512 + gx];
          tile[cur ^ 1][ly][lx] = v;
        }
      }
    }
    float g = 0.f;
    #pragma unroll
    for (int dy = 0; dy < 3; ++dy)
      #pragma unroll
      for (int dx = 0; dx < 3; ++dx)
        g += w4b[c * 9 + dy * 3 + dx] * tile[cur][ty + dy][tx + 3 + dx];
    float m = v2[c] * g;
    const float* mc = m2T + c * 64;
    #pragma unroll
    for (int o = 0; o < 64; ++o) acc[o] += mc[o] * m;
  }
  for (int c = 0; c < 64; ++c) {
    float hv = high[c * PP + p];
    const float* wc = pjT + c * 64;
    #pragma unroll
    for (int o = 0; o < 64; ++o) acc[o] += wc[o] * hv;
  }
  #pragma unroll
  for (int o = 0; o < 64; ++o) xo[o * PP + p] = acc[o];
}

// ---------------- LN2 + fin 1x1 64->340, striped ----------------
__global__ __launch_bounds__(256) void k_fin_s(const float* __restrict__ xo,
    const float* __restrict__ w, const float* __restrict__ b,
    const float* __restrict__ fw, float* __restrict__ pins, int rs, int base) {
  int p0 = rs * 512 + blockIdx.x * 64;
  __shared__ float ldsY[64][68];
  int tid = threadIdx.x;
  if (tid < 64) {
    int p = p0 + tid;
    float v[64]; float mu = 0.f;
    #pragma unroll
    for (int c = 0; c < 64; ++c) { v[c] = xo[c * PP + p]; mu += v[c]; }
    mu *= (1.f / 64.f);
    float s = 0.f;
    #pragma unroll
    for (int c = 0; c < 64; ++c) { float d = v[c] - mu; s += d * d; }
    float rsq = rsqrtf(s * (1.f / 64.f) + EPSLN);
    #pragma unroll
    for (int c = 0; c < 64; ++c) ldsY[tid][c] = (v[c] - mu) * rsq * w[c] + b[c];
  }
  __syncthreads();
  int px = tid & 63, chunk = tid >> 6;
  float a[64];
  const float4* row4 = (const float4*)&ldsY[px][0];
  #pragma unroll
  for (int c4 = 0; c4 < 16; ++c4) {
    float4 v4 = row4[c4];
    a[c4 * 4 + 0] = v4.x; a[c4 * 4 + 1] = v4.y; a[c4 * 4 + 2] = v4.z; a[c4 * 4 + 3] = v4.w;
  }
  int gp = p0 + px;
  int gy = gp >> 9, gx = gp & 511;
  int lr = gy - base;
  for (int i = 0; i < 85; ++i) {
    int o = chunk * 85 + i;
    const float* wr = fw + o * 64;
    float s = 0.f;
    #pragma unroll
    for (int c = 0; c < 64; ++c) s += wr[c] * a[c];
    pins[o * STR + lr * 512 + gx] = s;
  }
}

// ---------------- fused FFN tail: gelu(dw(x1))*x2 -> LDS -> 170->64 matmul + residual ----------
__global__ __launch_bounds__(256) void k_ffnout_s(const float* __restrict__ pins,
    const float* __restrict__ www, const float* __restrict__ wwb,
    const float* __restrict__ whw, const float* __restrict__ whb,
    const float* __restrict__ foT, const float* __restrict__ xo,
    float* __restrict__ out, int r0) {
  int ry = blockIdx.x >> 3;                 // row within stripe [0,128)
  int gx0 = (blockIdx.x & 7) * 64;
  int lr = ry + 5;
  __shared__ float ldsT[170][64];
  int px = threadIdx.x & 63, hcq = threadIdx.x >> 6;
  int gx = gx0 + px;
  for (int i = 0; i < 43; ++i) {
    int hc = hcq * 43 + i;
    if (hc >= 170) break;
    const float* x1 = pins + hc * STR;
    float s = wwb[hc] + whb[hc];
    #pragma unroll
    for (int j = 0; j < 11; ++j) {
      int ix = gx + j - 5;
      if (ix >= 0 && ix < 512) s += www[hc * 11 + j] * x1[lr * 512 + ix];
    }
    #pragma unroll
    for (int j = 0; j < 11; ++j) {
      int gy2 = r0 + ry + j - 5;
      if (gy2 >= 0 && gy2 < 512) s += whw[hc * 11 + j] * x1[(ry + j) * 512 + gx];
    }
    float g = 0.5f * s * (1.f + erff(s * 0.70710678118654752440f));
    ldsT[hc][px] = g * pins[(170 + hc) * STR + lr * 512 + gx];
  }
  __syncthreads();
  float acc[16];
  #pragma unroll
  for (int i = 0; i < 16; ++i) acc[i] = 0.f;
  for (int hc = 0; hc < 170; ++hc) {
    float tv = ldsT[hc][px];
    const float* wr = foT + hc * 64 + hcq * 16;
    #pragma unroll
    for (int i = 0; i < 16; ++i) acc[i] += wr[i] * tv;
  }
  int p = (r0 + ry) * 512 + gx0 + px;
  #pragma unroll
  for (int i = 0; i < 16; ++i) {
    int o = hcq * 16 + i;
    out[o * PP + p] = xo[o * PP + p] + acc[i];
  }
}

extern "C" void kernel_launch(void* const* d_in, const int* in_sizes, int n_in,
                              void* d_out, int out_size, void* d_ws, size_t ws_size,
                              hipStream_t stream) {
  (void)in_sizes; (void)n_in; (void)out_size;
  if (ws_size < (size_t)WS_NEEDED_FLOATS * 4) return;   // diagnostic guard
  const float* x        = (const float*)d_in[0];
  const float* ln1_w    = (const float*)d_in[1];
  const float* ln1_b    = (const float*)d_in[2];
  const float* temp     = (const float*)d_in[3];
  const float* dww_w    = (const float*)d_in[4];
  const float* dww_b    = (const float*)d_in[5];
  const float* dwh_w    = (const float*)d_in[6];
  const float* dwh_b    = (const float*)d_in[7];
  const float* dwhw_w   = (const float*)d_in[8];
  const float* dwhw_b   = (const float*)d_in[9];
  const float* conv1_w  = (const float*)d_in[10];
  const float* qkv_w    = (const float*)d_in[11];
  const float* qkvdw_w  = (const float*)d_in[12];
  const float* conv2_w  = (const float*)d_in[13];
  const float* conv3_w  = (const float*)d_in[14];
  const float* conv4a_w = (const float*)d_in[15];
  const float* conv4b_w = (const float*)d_in[16];
  const float* projo_w  = (const float*)d_in[17];
  const float* ln2_w    = (const float*)d_in[18];
  const float* ln2_b    = (const float*)d_in[19];
  const float* fin_w    = (const float*)d_in[20];
  const float* fdww_w   = (const float*)d_in[21];
  const float* fdww_b   = (const float*)d_in[22];
  const float* fdwh_w   = (const float*)d_in[23];
  const float* fdwh_b   = (const float*)d_in[24];
  const float* fout_w   = (const float*)d_in[25];

  float* ws  = (float*)d_ws;
  float* out = (float*)d_out;

  float* Y    = ws + OFF_Y;
  float* XO   = ws + OFF_XO;
  float* HIGH = ws + OFF_HIGH;
  float* T4   = ws + OFF_T4;
  float* PINS = ws + OFF_PINS;
  float* XD   = ws + OFF_XD;
  float* QKV0 = ws + OFF_QKV0;
  float* QKVB = ws + OFF_QKVB;
  float* RN   = ws + OFF_RNORM;
  float* ATT  = ws + OFF_ATTN;
  float* VMX  = ws + OFF_VMAX;
  float* VMN  = ws + OFF_VMEAN;
  float* V2   = ws + OFF_V2;
  float* M2T  = ws + OFF_M2T;
  float* C1T  = ws + OFF_C1T;
  float* PJT  = ws + OFF_PJT;
  float* C4T  = ws + OFF_C4T;
  float* FOT  = ws + OFF_FOT;
  float* K1   = ws + OFF_K1;
  float* K2   = ws + OFF_K2;
  float* HC   = ws + OFF_HC;

  k_wT<<<43, 256, 0, stream>>>(conv1_w, projo_w, conv4a_w, fout_w, C1T, PJT, C4T, FOT);
  k_prep<<<20, 256, 0, stream>>>(dww_w, dww_b, dwh_w, dwh_b, dwhw_w, dwhw_b,
                                 conv1_w, K1, K2, HC);
  k_ln1<<<1024, 256, 0, stream>>>(x, ln1_w, ln1_b, Y);
  k_pool<<<1024, 256, 0, stream>>>(Y, XD);
  k_qkv0<<<3072, 256, 0, stream>>>(XD, qkv_w, QKV0);
  k_qkvdw<<<3072, 256, 0, stream>>>(QKV0, qkvdw_w, QKVB);
  k_qknorm<<<128, 256, 0, stream>>>(QKVB, RN);
  k_attn<<<64, 256, 0, stream>>>(QKVB, RN, temp, ATT);
  k_vstat<<<64, 256, 0, stream>>>(QKVB, VMX, VMN);
  k_v2<<<1, 64, 0, stream>>>(VMX, VMN, conv2_w, conv3_w, V2);
  k_m2<<<16, 256, 0, stream>>>(ATT, projo_w, M2T);
  k_dwhigh<<<1024, 256, 0, stream>>>(Y, dww_w, dww_b, dwh_w, dwh_b,
                                     dwhw_w, dwhw_b, C1T, K1, K2, HC, HIGH);
  k_conv4a<<<1024, 256, 0, stream>>>(Y, C4T, T4);
  k_lowproj<<<1024, 256, 0, stream>>>(T4, conv4b_w, V2, M2T, HIGH, PJT, x, XO);

  for (int s = 0; s < 4; ++s) {
    int r0 = s * RSTRIPE;
    int base = r0 - 5;
    int rs = base < 0 ? 0 : base;
    int re = r0 + RSTRIPE + 5; if (re > 512) re = 512;
    int nrow = re - rs;
    k_fin_s<<<nrow * 8, 256, 0, stream>>>(XO, ln2_w, ln2_b, fin_w, PINS, rs, base);
    k_ffnout_s<<<1024, 256, 0, stream>>>(PINS, fdww_w, fdww_b, fdwh_w, fdwh_b,
                                         FOT, XO, out, r0);
  }
}

// Round 4
// 2168.760 us; speedup vs baseline: 1.4521x; 1.4521x over previous
//
#include <hip/hip_runtime.h>
#include <math.h>

#define PP 262144   // 512*512
#define WW 512
#define EPSLN 1e-5f
#define RSTRIPE 128
#define STR 70656   // (RSTRIPE+10)*512

// ---------------- workspace layout (float offsets), total 52,205,568 floats = 208.8 MB ----
#define OFF_Y     0
#define OFF_XO    0
#define OFF_HIGH  16777216
#define OFF_T4    33554432
#define OFF_PINS  16777216
#define OFF_XD    50331648
#define OFF_QKV0  50593792
#define OFF_QKVB  51380224
#define OFF_RNORM 52166656
#define OFF_ATTN  52166784
#define OFF_VMAX  52168832
#define OFF_VMEAN 52168896
#define OFF_V2    52168960
#define OFF_M2T   52169024
#define OFF_C1T   52173120
#define OFF_PJT   52181312
#define OFF_C4T   52185408
#define OFF_FOT   52189504
#define OFF_K1    52200384
#define OFF_K2    52202944
#define OFF_HC    52205504
#define WS_NEEDED_FLOATS 52205568

// ---------------- weight transposes (tiny, once per launch) ----------------
__global__ __launch_bounds__(256) void k_wT(const float* __restrict__ c1, const float* __restrict__ pj,
                     const float* __restrict__ c4, const float* __restrict__ fo,
                     float* __restrict__ c1T, float* __restrict__ pjT,
                     float* __restrict__ c4T, float* __restrict__ foT) {
  int t = blockIdx.x * 256 + threadIdx.x;
  if (t < 8192)  c1T[(t & 127) * 64 + (t >> 7)] = c1[t];       // (64,128) -> [c][o]
  if (t < 8192 && (t & 127) < 64) pjT[(t & 127) * 64 + (t >> 7)] = pj[t];  // high half only
  if (t < 4096)  c4T[(t & 63) * 64 + (t >> 6)]  = c4[t];       // (64,64)  -> [c][o]
  if (t < 10880) foT[(t % 170) * 64 + (t / 170)] = fo[t];      // (64,170) -> [hc][o]
}

// ---------------- composite 3x13 / 13x3 kernels + constant term ----------------
__global__ __launch_bounds__(256) void k_prep(const float* __restrict__ ww, const float* __restrict__ wwb,
    const float* __restrict__ wh, const float* __restrict__ whb,
    const float* __restrict__ w3, const float* __restrict__ b3,
    const float* __restrict__ c1,
    float* __restrict__ K1, float* __restrict__ K2, float* __restrict__ HC) {
  int t = blockIdx.x * 256 + threadIdx.x;
  if (t < 2496) {                       // K1: 64 ch x (3 rows x 13 cols)
    int c = t / 39, r = t % 39, ey = r / 13, ex = r % 13;
    float s = 0.f;
    for (int dx = 0; dx < 3; ++dx) {
      int j = ex - dx;
      if (j >= 0 && j < 11) s += w3[c * 9 + ey * 3 + dx] * ww[c * 11 + j];
    }
    K1[c * 40 + r] = s;
  } else if (t < 4992) {                // K2: 64 ch x (13 rows x 3 cols)
    int u = t - 2496;
    int c = u / 39, r = u % 39, ey = r / 3, ex = r % 3;
    float s = 0.f;
    for (int dy = 0; dy < 3; ++dy) {
      int j = ey - dy;
      if (j >= 0 && j < 11) s += w3[(64 + c) * 9 + dy * 3 + ex] * wh[c * 11 + j];
    }
    K2[c * 40 + r] = s;
  } else if (t < 5056) {                // hconst[o]
    int o = t - 4992;
    float s = 0.f;
    for (int c = 0; c < 64; ++c) {
      float g1 = 0.f, g2 = 0.f;
      for (int k = 0; k < 9; ++k) { g1 += w3[c * 9 + k]; g2 += w3[(64 + c) * 9 + k]; }
      float cA = b3[c] + wwb[c] * g1;
      float cB = b3[64 + c] + whb[c] * g2;
      s += c1[o * 128 + c] * cA + c1[o * 128 + 64 + c] * cB;
    }
    HC[o] = s;
  }
}

// ---------------- LayerNorm over channels (thread = pixel) ----------------
__global__ __launch_bounds__(256) void k_ln1(const float* __restrict__ x,
    const float* __restrict__ w, const float* __restrict__ b, float* __restrict__ y) {
  int p = blockIdx.x * 256 + threadIdx.x;
  float v[64]; float mu = 0.f;
  #pragma unroll
  for (int c = 0; c < 64; ++c) { v[c] = x[c * PP + p]; mu += v[c]; }
  mu *= (1.f / 64.f);
  float s = 0.f;
  #pragma unroll
  for (int c = 0; c < 64; ++c) { float d = v[c] - mu; s += d * d; }
  float rs = rsqrtf(s * (1.f / 64.f) + EPSLN);
  #pragma unroll
  for (int c = 0; c < 64; ++c) y[c * PP + p] = (v[c] - mu) * rs * w[c] + b[c];
}

// ---------------- 8x8 avg pool of y -> xd (64x64x64) ----------------
__global__ __launch_bounds__(256) void k_pool(const float* __restrict__ y, float* __restrict__ xd) {
  int t = blockIdx.x * 256 + threadIdx.x;
  int c = t >> 12, cell = t & 4095;
  int cy = cell >> 6, cx = cell & 63;
  const float* base = y + c * PP + (cy * 8) * WW + cx * 8;
  float s = 0.f;
  #pragma unroll
  for (int r = 0; r < 8; ++r)
    #pragma unroll
    for (int i = 0; i < 8; ++i) s += base[r * WW + i];
  xd[t] = s * (1.f / 64.f);
}

// ---------------- qkv 1x1 conv 64->192 on 64x64 ----------------
__global__ __launch_bounds__(256) void k_qkv0(const float* __restrict__ xd,
    const float* __restrict__ w, float* __restrict__ q0) {
  int t = blockIdx.x * 256 + threadIdx.x;
  int o = t >> 12, pd = t & 4095;
  float acc = 0.f;
  #pragma unroll
  for (int c = 0; c < 64; ++c) acc += w[o * 64 + c] * xd[c * 4096 + pd];
  q0[t] = acc;
}

// ---------------- qkv depthwise 3x3 (192 ch, 64x64, pad1, no bias) ----------------
__global__ __launch_bounds__(256) void k_qkvdw(const float* __restrict__ q0,
    const float* __restrict__ w, float* __restrict__ qb) {
  int t = blockIdx.x * 256 + threadIdx.x;
  int o = t >> 12, pd = t & 4095;
  int yy = pd >> 6, xx = pd & 63;
  float acc = 0.f;
  #pragma unroll
  for (int dy = 0; dy < 3; ++dy) {
    int iy = yy + dy - 1;
    if (iy < 0 || iy >= 64) continue;
    #pragma unroll
    for (int dx = 0; dx < 3; ++dx) {
      int ix = xx + dx - 1;
      if (ix < 0 || ix >= 64) continue;
      acc += w[o * 9 + dy * 3 + dx] * q0[o * 4096 + iy * 64 + ix];
    }
  }
  qb[t] = acc;
}

// ---------------- 1/L2norm of q,k rows (128 rows x 4096) ----------------
__global__ __launch_bounds__(256) void k_qknorm(const float* __restrict__ qb, float* __restrict__ rnorm) {
  int r = blockIdx.x;
  const float* row = qb + r * 4096;
  float s = 0.f;
  for (int i = threadIdx.x; i < 4096; i += 256) { float v = row[i]; s += v * v; }
  __shared__ float red[256];
  red[threadIdx.x] = s; __syncthreads();
  for (int off = 128; off > 0; off >>= 1) {
    if (threadIdx.x < off) red[threadIdx.x] += red[threadIdx.x + off];
    __syncthreads();
  }
  if (threadIdx.x == 0) rnorm[r] = 1.f / fmaxf(sqrtf(red[0]), 1e-12f);
}

// ---------------- attn row (h,c): 32 dots over 4096 + softmax ----------------
__global__ __launch_bounds__(256) void k_attn(const float* __restrict__ qb,
    const float* __restrict__ rnorm, const float* __restrict__ temp, float* __restrict__ attn) {
  int h = blockIdx.x >> 5, c = blockIdx.x & 31;
  const float* qrow = qb + (h * 32 + c) * 4096;
  const float* kb   = qb + (64 + h * 32) * 4096;
  float acc[32];
  #pragma unroll
  for (int d = 0; d < 32; ++d) acc[d] = 0.f;
  for (int pd = threadIdx.x; pd < 4096; pd += 256) {
    float qv = qrow[pd];
    #pragma unroll
    for (int d = 0; d < 32; ++d) acc[d] += qv * kb[d * 4096 + pd];
  }
  __shared__ float red[32][257];
  __shared__ float srow[32];
  #pragma unroll
  for (int d = 0; d < 32; ++d) red[d][threadIdx.x] = acc[d];
  __syncthreads();
  if (threadIdx.x < 32) {
    int d = threadIdx.x;
    float s = 0.f;
    for (int j = 0; j < 256; ++j) s += red[d][j];
    s *= rnorm[h * 32 + c] * rnorm[64 + h * 32 + d] * temp[h];
    srow[d] = s;
  }
  __syncthreads();
  if (threadIdx.x == 0) {
    float m = srow[0];
    for (int d = 1; d < 32; ++d) m = fmaxf(m, srow[d]);
    float sum = 0.f;
    float e[32];
    for (int d = 0; d < 32; ++d) { e[d] = expf(srow[d] - m); sum += e[d]; }
    float r = 1.f / sum;
    for (int d = 0; d < 32; ++d) attn[(h * 32 + c) * 32 + d] = e[d] * r;
  }
}

// ---------------- v spatial max/mean per channel ----------------
__global__ __launch_bounds__(256) void k_vstat(const float* __restrict__ qb,
    float* __restrict__ vmax, float* __restrict__ vmean) {
  int ci = blockIdx.x;
  const float* row = qb + (128 + ci) * 4096;
  float mx = -1e30f, s = 0.f;
  for (int i = threadIdx.x; i < 4096; i += 256) { float v = row[i]; mx = fmaxf(mx, v); s += v; }
  __shared__ float rm[256], rs[256];
  rm[threadIdx.x] = mx; rs[threadIdx.x] = s; __syncthreads();
  for (int off = 128; off > 0; off >>= 1) {
    if (threadIdx.x < off) {
      rm[threadIdx.x] = fmaxf(rm[threadIdx.x], rm[threadIdx.x + off]);
      rs[threadIdx.x] += rs[threadIdx.x + off];
    }
    __syncthreads();
  }
  if (threadIdx.x == 0) { vmax[ci] = rm[0]; vmean[ci] = rs[0] * (1.f / 4096.f); }
}

// ---------------- v2[c] = conv2(vmax) + conv3(vmean) ----------------
__global__ void k_v2(const float* __restrict__ vmax, const float* __restrict__ vmean,
    const float* __restrict__ w2, const float* __restrict__ w3, float* __restrict__ v2) {
  int c = threadIdx.x;
  float s = 0.f;
  #pragma unroll
  for (int ci = 0; ci < 64; ++ci) s += w2[c * 64 + ci] * vmax[ci] + w3[c * 64 + ci] * vmean[ci];
  v2[c] = s;
}

// ---------------- M2[o,c=h*32+d], stored [c][o] ----------------
__global__ __launch_bounds__(256) void k_m2(const float* __restrict__ attn,
    const float* __restrict__ pj, float* __restrict__ m2T) {
  int t = blockIdx.x * 256 + threadIdx.x;   // 4096
  int o = t >> 6, c = t & 63;
  int h = c >> 5, d = c & 31;
  float s = 0.f;
  #pragma unroll
  for (int cc = 0; cc < 32; ++cc)
    s += pj[o * 128 + 64 + h * 32 + cc] * attn[(h * 32 + cc) * 32 + d];
  m2T[c * 64 + o] = s;
}

// ---------------- fused high path: interior = composite 3x13/13x3 + 1x1; boundary = exact ring ----
__global__ __launch_bounds__(256) void k_dwhigh(const float* __restrict__ y,
    const float* __restrict__ ww, const float* __restrict__ wwb,
    const float* __restrict__ wh, const float* __restrict__ whb,
    const float* __restrict__ w3, const float* __restrict__ b3,
    const float* __restrict__ c1T,
    const float* __restrict__ K1, const float* __restrict__ K2,
    const float* __restrict__ HC, float* __restrict__ high) {
  int bx = blockIdx.x & 31, by = blockIdx.x >> 5;
  int x0 = bx * 16, y0 = by * 16;
  int tx = threadIdx.x & 15, ty = threadIdx.x >> 4;
  int t = threadIdx.x;
  __shared__ float tyy[2][28][40];
  __shared__ float ha[18][18];
  __shared__ float hb[18][18];
  float acc[64];
  bool interior = (bx > 0 && bx < 31 && by > 0 && by < 31);
  int p = (y0 + ty) * 512 + x0 + tx;

  if (interior) {
    #pragma unroll
    for (int o = 0; o < 64; ++o) acc[o] = HC[o];
    int srow = t >> 3, sq = t & 7;
    const float* gsrc = y + (y0 - 6 + srow) * 512 + (x0 - 8) + sq * 4;
    if (t < 224) *(float4*)&tyy[0][srow][sq * 4] = *(const float4*)gsrc;
    for (int c = 0; c < 64; ++c) {
      int cur = c & 1;
      __syncthreads();
      if (c < 63 && t < 224)
        *(float4*)&tyy[cur ^ 1][srow][sq * 4] = *(const float4*)(gsrc + (c + 1) * PP);
      float SA = 0.f, SB = 0.f;
      const float* k1c = K1 + c * 40;
      const float* k2c = K2 + c * 40;
      #pragma unroll
      for (int ey = 0; ey < 3; ++ey)
        #pragma unroll
        for (int ex = 0; ex < 13; ++ex)
          SA += k1c[ey * 13 + ex] * tyy[cur][ty + 5 + ey][tx + 2 + ex];
      #pragma unroll
      for (int ey = 0; ey < 13; ++ey)
        #pragma unroll
        for (int ex = 0; ex < 3; ++ex)
          SB += k2c[ey * 3 + ex] * tyy[cur][ty + ey][tx + 7 + ex];
      const float* wc1 = c1T + c * 64;
      const float* wc2 = c1T + (64 + c) * 64;
      #pragma unroll
      for (int o = 0; o < 64; ++o) acc[o] += wc1[o] * SA + wc2[o] * SB;
    }
  } else {
    #pragma unroll
    for (int o = 0; o < 64; ++o) acc[o] = 0.f;
    for (int idx = t; idx < 896; idx += 256) {
      int ly = idx >> 5, lx = idx & 31;
      int gy = y0 - 6 + ly, gx = x0 - 8 + lx;
      float v = 0.f;
      if (gy >= 0 && gy < 512 && gx >= 0 && gx < 512) v = y[gy * 512 + gx];
      tyy[0][ly][lx] = v;
    }
    for (int c = 0; c < 64; ++c) {
      int cur = c & 1;
      __syncthreads();
      if (c < 63) {
        for (int idx = t; idx < 896; idx += 256) {
          int ly = idx >> 5, lx = idx & 31;
          int gy = y0 - 6 + ly, gx = x0 - 8 + lx;
          float v = 0.f;
          if (gy >= 0 && gy < 512 && gx >= 0 && gx < 512) v = y[(c + 1) * PP + gy * 512 + gx];
          tyy[cur ^ 1][ly][lx] = v;
        }
      }
      for (int idx = t; idx < 324; idx += 256) {
        int ly = idx / 18, lx = idx % 18;
        int gy = y0 - 1 + ly, gx = x0 - 1 + lx;
        float a = 0.f, b = 0.f;
        if (gy >= 0 && gy < 512 && gx >= 0 && gx < 512) {
          a = wwb[c]; b = whb[c];
          #pragma unroll
          for (int i = 0; i < 11; ++i) a += ww[c * 11 + i] * tyy[cur][ly + 5][lx + 2 + i];
          #pragma unroll
          for (int i = 0; i < 11; ++i) b += wh[c * 11 + i] * tyy[cur][ly + i][lx + 7];
        }
        ha[ly][lx] = a; hb[ly][lx] = b;
      }
      __syncthreads();
      float sa = b3[c], sb = b3[64 + c];
      #pragma unroll
      for (int dy = 0; dy < 3; ++dy)
        #pragma unroll
        for (int dx = 0; dx < 3; ++dx) {
          sa += w3[c * 9 + dy * 3 + dx]        * ha[ty + dy][tx + dx];
          sb += w3[(64 + c) * 9 + dy * 3 + dx] * hb[ty + dy][tx + dx];
        }
      const float* wc1 = c1T + c * 64;
      const float* wc2 = c1T + (64 + c) * 64;
      #pragma unroll
      for (int o = 0; o < 64; ++o) acc[o] += wc1[o] * sa + wc2[o] * sb;
    }
  }
  #pragma unroll
  for (int o = 0; o < 64; ++o) high[o * PP + p] = acc[o];
}

// ---------------- conv4a: 1x1 64->64 on y ----------------
__global__ __launch_bounds__(256) void k_conv4a(const float* __restrict__ y,
    const float* __restrict__ c4T, float* __restrict__ t4) {
  int p = blockIdx.x * 256 + threadIdx.x;
  float acc[64];
  #pragma unroll
  for (int o = 0; o < 64; ++o) acc[o] = 0.f;
  for (int c = 0; c < 64; ++c) {
    float vy = y[c * PP + p];
    const float* wc = c4T + c * 64;
    #pragma unroll
    for (int o = 0; o < 64; ++o) acc[o] += wc[o] * vy;
  }
  #pragma unroll
  for (int o = 0; o < 64; ++o) t4[o * PP + p] = acc[o];
}

// ---------------- fused: g=dw3x3(t4); m=v2*g; xo = x + M2@m + projo_high@high ----------------
__global__ __launch_bounds__(256) void k_lowproj(const float* __restrict__ t4,
    const float* __restrict__ w4b, const float* __restrict__ v2,
    const float* __restrict__ m2T, const float* __restrict__ high,
    const float* __restrict__ pjT, const float* __restrict__ x,
    float* __restrict__ xo) {
  int bx = blockIdx.x & 31, by = blockIdx.x >> 5;
  int x0 = bx * 16, y0 = by * 16;
  int tx = threadIdx.x & 15, ty = threadIdx.x >> 4;
  int t = threadIdx.x;
  int p = (y0 + ty) * 512 + x0 + tx;
  __shared__ float tile[2][18][40];
  bool interior = (bx > 0 && bx < 31 && by > 0 && by < 31);
  float acc[64];
  #pragma unroll
  for (int o = 0; o < 64; ++o) acc[o] = x[o * PP + p];

  int srow = t >> 3, sq = t & 7;
  const float* gsrc = t4 + (y0 - 1 + srow) * 512 + (x0 - 4) + sq * 4;
  if (interior) {
    if (t < 144) *(float4*)&tile[0][srow][sq * 4] = *(const float4*)gsrc;
  } else {
    for (int idx = t; idx < 576; idx += 256) {
      int ly = idx >> 5, lx = idx & 31;
      int gy = y0 - 1 + ly, gx = x0 - 4 + lx;
      float v = 0.f;
      if (gy >= 0 && gy < 512 && gx >= 0 && gx < 512) v = t4[gy * 512 + gx];
      tile[0][ly][lx] = v;
    }
  }
  for (int c = 0; c < 64; ++c) {
    int cur = c & 1;
    __syncthreads();
    if (c < 63) {
      if (interior) {
        if (t < 144) *(float4*)&tile[cur ^ 1][srow][sq * 4] = *(const float4*)(gsrc + (c + 1) * PP);
      } else {
        for (int idx = t; idx < 576; idx += 256) {
          int ly = idx >> 5, lx = idx & 31;
          int gy = y0 - 1 + ly, gx = x0 - 4 + lx;
          float v = 0.f;
          if (gy >= 0 && gy < 512 && gx >= 0 && gx < 512) v = t4[(c + 1) * PP + gy * 512 + gx];
          tile[cur ^ 1][ly][lx] = v;
        }
      }
    }
    float g = 0.f;
    #pragma unroll
    for (int dy = 0; dy < 3; ++dy)
      #pragma unroll
      for (int dx = 0; dx < 3; ++dx)
        g += w4b[c * 9 + dy * 3 + dx] * tile[cur][ty + dy][tx + 3 + dx];
    float m = v2[c] * g;
    const float* mc = m2T + c * 64;
    #pragma unroll
    for (int o = 0; o < 64; ++o) acc[o] += mc[o] * m;
  }
  for (int c = 0; c < 64; ++c) {
    float hv = high[c * PP + p];
    const float* wc = pjT + c * 64;
    #pragma unroll
    for (int o = 0; o < 64; ++o) acc[o] += wc[o] * hv;
  }
  #pragma unroll
  for (int o = 0; o < 64; ++o) xo[o * PP + p] = acc[o];
}

// ---------------- LN2 + fin 1x1 64->340, striped ----------------
__global__ __launch_bounds__(256) void k_fin_s(const float* __restrict__ xo,
    const float* __restrict__ w, const float* __restrict__ b,
    const float* __restrict__ fw, float* __restrict__ pins, int rs, int base) {
  int p0 = rs * 512 + blockIdx.x * 64;
  __shared__ float ldsY[64][68];
  int tid = threadIdx.x;
  if (tid < 64) {
    int p = p0 + tid;
    float v[64]; float mu = 0.f;
    #pragma unroll
    for (int c = 0; c < 64; ++c) { v[c] = xo[c * PP + p]; mu += v[c]; }
    mu *= (1.f / 64.f);
    float s = 0.f;
    #pragma unroll
    for (int c = 0; c < 64; ++c) { float d = v[c] - mu; s += d * d; }
    float rsq = rsqrtf(s * (1.f / 64.f) + EPSLN);
    #pragma unroll
    for (int c = 0; c < 64; ++c) ldsY[tid][c] = (v[c] - mu) * rsq * w[c] + b[c];
  }
  __syncthreads();
  int px = tid & 63, chunk = tid >> 6;
  float a[64];
  const float4* row4 = (const float4*)&ldsY[px][0];
  #pragma unroll
  for (int c4 = 0; c4 < 16; ++c4) {
    float4 v4 = row4[c4];
    a[c4 * 4 + 0] = v4.x; a[c4 * 4 + 1] = v4.y; a[c4 * 4 + 2] = v4.z; a[c4 * 4 + 3] = v4.w;
  }
  int gp = p0 + px;
  int gy = gp >> 9, gx = gp & 511;
  int lr = gy - base;
  for (int i = 0; i < 85; ++i) {
    int o = chunk * 85 + i;
    const float* wr = fw + o * 64;
    float s = 0.f;
    #pragma unroll
    for (int c = 0; c < 64; ++c) s += wr[c] * a[c];
    pins[o * STR + lr * 512 + gx] = s;
  }
}

// ---------------- FFN depthwise: 64x64 tile per (hc, tile); LDS halo; in-place gelu*x2 ----
__global__ __launch_bounds__(256) void k_ffndw2(float* __restrict__ pins,
    const float* __restrict__ www, const float* __restrict__ wwb,
    const float* __restrict__ whw, const float* __restrict__ whb, int r0) {
  int hc = blockIdx.x >> 4;
  int tile = blockIdx.x & 15;
  int ty0 = (tile >> 3) << 6;          // 0 or 64 (stripe-local row)
  int x0 = (tile & 7) << 6;            // 0..448
  __shared__ float lds[74][80];        // x1 halo tile, origin (stripe row ty0-?; col x0-8)
  const float* x1 = pins + hc * STR;
  for (int idx = threadIdx.x; idx < 5920; idx += 256) {
    int L = idx / 80, cx = idx - L * 80;
    int gy = r0 - 5 + ty0 + L;         // buffer row ty0+L maps to this image row
    int gx = x0 - 8 + cx;
    float v = 0.f;
    if (gy >= 0 && gy < 512 && gx >= 0 && gx < 512)
      v = x1[(ty0 + L) * 512 + gx];
    lds[L][cx] = v;
  }
  __syncthreads();
  int c = threadIdx.x & 63;            // one column per lane -> conflict-free LDS
  int rw = (threadIdx.x >> 6) << 4;    // 16 rows per thread
  float W[26];
  #pragma unroll
  for (int m = 0; m < 26; ++m) W[m] = lds[rw + m][c + 8];
  float bias = wwb[hc] + whb[hc];
  float o16[16];
  #pragma unroll
  for (int k = 0; k < 16; ++k) {
    float s = bias;
    #pragma unroll
    for (int j = 0; j < 11; ++j) s += whw[hc * 11 + j] * W[k + j];   // vertical 11x1
    o16[k] = s;
  }
  #pragma unroll
  for (int k = 0; k < 16; ++k) {
    float s = 0.f;
    #pragma unroll
    for (int i = 0; i < 11; ++i) s += www[hc * 11 + i] * lds[rw + k + 5][c + 3 + i]; // horiz 1x11
    o16[k] += s;
  }
  float* x2base = pins + (170 + hc) * STR;
  #pragma unroll
  for (int k = 0; k < 16; ++k) {
    int ry = ty0 + rw + k;
    float s = o16[k];
    float g = 0.5f * s * (1.f + erff(s * 0.70710678118654752440f));
    float* p2 = x2base + (ry + 5) * 512 + x0 + c;
    *p2 = g * (*p2);
  }
}

// ---------------- fout 1x1 170->64 + residual, striped ----------------
__global__ __launch_bounds__(256) void k_fout_s(const float* __restrict__ pins,
    const float* __restrict__ foT, const float* __restrict__ xo,
    float* __restrict__ out, int r0) {
  int p0 = blockIdx.x * 64;
  int ry = p0 >> 9, gx0 = p0 & 511;
  int lr = ry + 5;
  __shared__ float ldsT[170][64];
  for (int idx = threadIdx.x; idx < 170 * 64; idx += 256) {
    int hc = idx >> 6, px = idx & 63;
    ldsT[hc][px] = pins[(170 + hc) * STR + lr * 512 + gx0 + px];
  }
  __syncthreads();
  int px = threadIdx.x & 63, chunk = threadIdx.x >> 6;
  float acc[16];
  #pragma unroll
  for (int i = 0; i < 16; ++i) acc[i] = 0.f;
  for (int hc = 0; hc < 170; ++hc) {
    float tv = ldsT[hc][px];
    const float* wr = foT + hc * 64 + chunk * 16;
    #pragma unroll
    for (int i = 0; i < 16; ++i) acc[i] += wr[i] * tv;
  }
  int p = (r0 + ry) * 512 + gx0 + px;
  #pragma unroll
  for (int i = 0; i < 16; ++i) {
    int o = chunk * 16 + i;
    out[o * PP + p] = xo[o * PP + p] + acc[i];
  }
}

extern "C" void kernel_launch(void* const* d_in, const int* in_sizes, int n_in,
                              void* d_out, int out_size, void* d_ws, size_t ws_size,
                              hipStream_t stream) {
  (void)in_sizes; (void)n_in; (void)out_size;
  if (ws_size < (size_t)WS_NEEDED_FLOATS * 4) return;   // diagnostic guard
  const float* x        = (const float*)d_in[0];
  const float* ln1_w    = (const float*)d_in[1];
  const float* ln1_b    = (const float*)d_in[2];
  const float* temp     = (const float*)d_in[3];
  const float* dww_w    = (const float*)d_in[4];
  const float* dww_b    = (const float*)d_in[5];
  const float* dwh_w    = (const float*)d_in[6];
  const float* dwh_b    = (const float*)d_in[7];
  const float* dwhw_w   = (const float*)d_in[8];
  const float* dwhw_b   = (const float*)d_in[9];
  const float* conv1_w  = (const float*)d_in[10];
  const float* qkv_w    = (const float*)d_in[11];
  const float* qkvdw_w  = (const float*)d_in[12];
  const float* conv2_w  = (const float*)d_in[13];
  const float* conv3_w  = (const float*)d_in[14];
  const float* conv4a_w = (const float*)d_in[15];
  const float* conv4b_w = (const float*)d_in[16];
  const float* projo_w  = (const float*)d_in[17];
  const float* ln2_w    = (const float*)d_in[18];
  const float* ln2_b    = (const float*)d_in[19];
  const float* fin_w    = (const float*)d_in[20];
  const float* fdww_w   = (const float*)d_in[21];
  const float* fdww_b   = (const float*)d_in[22];
  const float* fdwh_w   = (const float*)d_in[23];
  const float* fdwh_b   = (const float*)d_in[24];
  const float* fout_w   = (const float*)d_in[25];

  float* ws  = (float*)d_ws;
  float* out = (float*)d_out;

  float* Y    = ws + OFF_Y;
  float* XO   = ws + OFF_XO;
  float* HIGH = ws + OFF_HIGH;
  float* T4   = ws + OFF_T4;
  float* PINS = ws + OFF_PINS;
  float* XD   = ws + OFF_XD;
  float* QKV0 = ws + OFF_QKV0;
  float* QKVB = ws + OFF_QKVB;
  float* RN   = ws + OFF_RNORM;
  float* ATT  = ws + OFF_ATTN;
  float* VMX  = ws + OFF_VMAX;
  float* VMN  = ws + OFF_VMEAN;
  float* V2   = ws + OFF_V2;
  float* M2T  = ws + OFF_M2T;
  float* C1T  = ws + OFF_C1T;
  float* PJT  = ws + OFF_PJT;
  float* C4T  = ws + OFF_C4T;
  float* FOT  = ws + OFF_FOT;
  float* K1   = ws + OFF_K1;
  float* K2   = ws + OFF_K2;
  float* HC   = ws + OFF_HC;

  k_wT<<<43, 256, 0, stream>>>(conv1_w, projo_w, conv4a_w, fout_w, C1T, PJT, C4T, FOT);
  k_prep<<<20, 256, 0, stream>>>(dww_w, dww_b, dwh_w, dwh_b, dwhw_w, dwhw_b,
                                 conv1_w, K1, K2, HC);
  k_ln1<<<1024, 256, 0, stream>>>(x, ln1_w, ln1_b, Y);
  k_pool<<<1024, 256, 0, stream>>>(Y, XD);
  k_qkv0<<<3072, 256, 0, stream>>>(XD, qkv_w, QKV0);
  k_qkvdw<<<3072, 256, 0, stream>>>(QKV0, qkvdw_w, QKVB);
  k_qknorm<<<128, 256, 0, stream>>>(QKVB, RN);
  k_attn<<<64, 256, 0, stream>>>(QKVB, RN, temp, ATT);
  k_vstat<<<64, 256, 0, stream>>>(QKVB, VMX, VMN);
  k_v2<<<1, 64, 0, stream>>>(VMX, VMN, conv2_w, conv3_w, V2);
  k_m2<<<16, 256, 0, stream>>>(ATT, projo_w, M2T);
  k_dwhigh<<<1024, 256, 0, stream>>>(Y, dww_w, dww_b, dwh_w, dwh_b,
                                     dwhw_w, dwhw_b, C1T, K1, K2, HC, HIGH);
  k_conv4a<<<1024, 256, 0, stream>>>(Y, C4T, T4);
  k_lowproj<<<1024, 256, 0, stream>>>(T4, conv4b_w, V2, M2T, HIGH, PJT, x, XO);

  for (int s = 0; s < 4; ++s) {
    int r0 = s * RSTRIPE;
    int base = r0 - 5;
    int rs = base < 0 ? 0 : base;
    int re = r0 + RSTRIPE + 5; if (re > 512) re = 512;
    int nrow = re - rs;
    k_fin_s<<<nrow * 8, 256, 0, stream>>>(XO, ln2_w, ln2_b, fin_w, PINS, rs, base);
    k_ffndw2<<<2720, 256, 0, stream>>>(PINS, fdww_w, fdww_b, fdwh_w, fdwh_b, r0);
    k_fout_s<<<1024, 256, 0, stream>>>(PINS, FOT, XO, out, r0);
  }
}